// Round 4
// baseline (121.137 us; speedup 1.0000x reference)
//
#include <hip/hip_runtime.h>

#define WN 128
#define KN 32
#define CN 9
#define NBND 129           // W+1 boundary positions
#define NEGF (-1e30f)

// jnp floor-mod based wrap: (x + pi) % (2pi) - pi
__device__ __forceinline__ float wrapf(float x) {
    const float PIf  = 3.14159265358979323846f;
    const float TPIf = 6.28318530717958647692f;
    float a = x + PIf;
    float r = fmodf(a, TPIf);
    if (r < 0.0f) r += TPIf;
    return r - PIf;
}

// Kernel 1: edge feasibility masks (32-bit kp-mask per (b,w,kn)), packed snr,
// and per-step union-of-masks Un[b][w] (bits = kp reachable from ANY kn).
__global__ __launch_bounds__(1024) void edge_kernel(const float* __restrict__ tok,
                                                    unsigned* __restrict__ Em,
                                                    float* __restrict__ snrP,
                                                    unsigned* __restrict__ Un) {
    __shared__ unsigned s_un;
    const int b = blockIdx.x / 127;
    const int w = blockIdx.x - b * 127;        // 0..126 (prev window)
    const int t = threadIdx.x;
    const int kp = t & 31;                     // prev token
    const int kn = t >> 5;                     // cur token (0..31)
    if (t == 0) s_un = 0u;
    __syncthreads();

    const float* Tp = tok + (((size_t)b * WN + w) * KN + kp) * CN;
    const float* Tc = tok + (((size_t)b * WN + w + 1) * KN + kn) * CN;

    float fe = Tp[4], fs = Tc[3];
    float fm = (fe + fs) * 0.5f;
    bool ok_f = (fm <= 0.0f) || (fabsf(fe - fs) / (fm > 0.0f ? fm : 1.0f) <= 0.05f);
    float dphi = wrapf(Tc[7] - Tp[8]);
    bool ok_p = fabsf(dphi) <= 0.5f;
    float ae = Tp[6], an = Tc[5];
    float am = fmaxf(ae, an);
    bool ok_a = (am <= 0.0f) || (fabsf(ae - an) / (am > 0.0f ? am : 1.0f) <= 0.5f);
    bool ok = (Tp[0] > 0.0f) && (Tc[0] > 0.0f) && ok_f && ok_p && ok_a;

    unsigned long long bal = __ballot(ok);
    int lw = t & 63;
    unsigned lo = (unsigned)(bal & 0xffffffffull);
    unsigned hi = (unsigned)(bal >> 32);
    if (lw == 0) {
        Em[((size_t)b * 127 + w) * KN + kn] = lo;
        if ((lo | hi) != 0u) atomicOr(&s_un, lo | hi);
    } else if (lw == 32) {
        Em[((size_t)b * 127 + w) * KN + kn] = hi;
    }

    if (kp == 0) snrP[((size_t)b * WN + (w + 1)) * KN + kn] = Tc[0];
    if (w == 0 && t < KN) snrP[(size_t)b * WN * KN + t] = tok[(((size_t)b * WN) * KN + t) * CN + 0];
    __syncthreads();
    if (t == 0) Un[b * 127 + w] = s_un;
}

// Kernel 2 (mega): blocks 0..B-1 = per-batch DP + greedy + backtrack + anchors
// into ws staging; blocks B.. zero-fill the 135MB output concurrently.
__global__ __launch_bounds__(1024) void mega_kernel(const float* __restrict__ tok,
                                                    const unsigned* __restrict__ Em,
                                                    const float* __restrict__ snrP,
                                                    const unsigned* __restrict__ Un,
                                                    float4* __restrict__ anchors,
                                                    int* __restrict__ meta,
                                                    float4* __restrict__ outz,
                                                    long total4, int B) {
    const int bid = blockIdx.x;
    if (bid >= B) {
        long i = (long)(bid - B) * 1024 + threadIdx.x;
        long stride = (long)(gridDim.x - B) * 1024;
        float4 z = make_float4(0.f, 0.f, 0.f, 0.f);
        for (; i < total4; i += stride) outz[i] = z;
        return;
    }

    const int b = bid;
    const int t = threadIdx.x;
    const float* T = tok + (size_t)b * WN * KN * CN;

    __shared__ unsigned sm_mask[127 * KN];
    __shared__ float sm_snr[WN * KN];
    __shared__ float sm_tot[WN * KN];
    __shared__ signed char sm_prev[WN * KN];
    __shared__ signed char sm_root[WN * KN];
    __shared__ unsigned long long s_key[KN];
    __shared__ unsigned char s_path[KN][WN];
    __shared__ float s_d[KN][NBND];
    __shared__ int s_we[KN];

    // ---- Phase A: stage masks + snr (all 16 waves)
    const unsigned* Eb = Em + (size_t)b * 127 * KN;
    const float* Sb = snrP + (size_t)b * WN * KN;
    for (int i = t; i < 127 * KN; i += 1024) sm_mask[i] = Eb[i];
    for (int i = t; i < WN * KN; i += 1024) sm_snr[i] = Sb[i];
    if (t < KN) s_key[t] = 0ull;
    __syncthreads();

    // ---- Phase B: register-resident Viterbi DP on wave 0.
    // Lane kn holds best[kn]; per-step masked max done via scalar loop over
    // the (sparse) union bits with v_readlane broadcasts. No LDS on the
    // loop-carried chain.
    if (t < 64) {
        const unsigned* Ub = Un + (size_t)b * 127;
        int unA = (t < 127) ? (int)Ub[t] : 0;               // un[0..63]
        int unB = (64 + t < 127) ? (int)Ub[64 + t] : 0;     // un[64..126]
        const int kn = t & 31;
        __builtin_amdgcn_s_setprio(1);

        float s0 = sm_snr[kn];
        float best = (s0 > 0.0f) ? s0 : NEGF;
        int root = kn;
        unsigned mask_cur = sm_mask[kn];          // masks for step w=1
        float sn_cur = sm_snr[KN + kn];

        for (int w = 1; w < WN; ++w) {
            // prefetch next step's mask/snr (hidden under this step's work)
            unsigned mask_nxt = 0; float sn_nxt = 0.0f;
            if (w < WN - 1) {
                mask_nxt = sm_mask[w * KN + kn];
                sn_nxt = sm_snr[(w + 1) * KN + kn];
            }
            const int wi = w - 1;
            int ua = __builtin_amdgcn_readlane(unA, wi & 63);
            int ub = __builtin_amdgcn_readlane(unB, wi & 63);
            unsigned un = (unsigned)((wi < 64) ? ua : ub);   // uniform -> SGPR

            float v = NEGF;
            int idx = 0;
            while (un) {                                      // ~3 bits avg, scalar
                int i = __builtin_ctz(un);
                un &= un - 1u;
                float bv = __int_as_float(
                    __builtin_amdgcn_readlane(__float_as_int(best), i));
                bool c = ((mask_cur >> i) & 1u) && (bv > v);  // strict > = first-argmax
                v = c ? bv : v;
                idx = c ? i : idx;
            }
            bool reached = v > -5e29f;                        // bf > NEG*0.5
            float te = v + sn_cur;
            int nr = __shfl(root, idx);                       // parallel root chain
            root = reached ? nr : root;
            if (t < 32) {
                sm_tot[w * KN + kn] = te;                     // consumed only if prev>=0
                sm_prev[w * KN + kn] = reached ? (signed char)idx : (signed char)-1;
                sm_root[w * KN + kn] = (signed char)(reached ? nr : 0);
            }
            best = reached ? te : NEGF;
            mask_cur = mask_nxt;
            sn_cur = sn_nxt;
        }
        __builtin_amdgcn_s_setprio(0);
    }
    __syncthreads();

    // ---- Phase C: greedy == per-root argmax(total), tie -> lowest flat idx
    for (int e = KN + t; e < WN * KN; e += 1024) {
        if (sm_prev[e] >= 0) {
            int r = sm_root[e];
            unsigned ubk = __float_as_uint(sm_tot[e]);
            ubk ^= (ubk >> 31) ? 0xFFFFFFFFu : 0x80000000u;
            unsigned long long key =
                ((unsigned long long)ubk << 32) | (unsigned long long)(0xFFFFFFFFu - (unsigned)e);
            atomicMax(&s_key[r], key);
        }
    }
    __syncthreads();

    // ---- Phase D: backtrack selected chain per root (32 lanes in parallel)
    if (t < KN) {
        unsigned long long key = s_key[t];
        int we = -1, e = -1;
        if (key != 0ull) {
            e = (int)(0xFFFFFFFFu - (unsigned)(key & 0xFFFFFFFFull));
            we = e >> 5;
            int k = e & 31;
            for (int w = we; w > 0; --w) {
                s_path[t][w] = (unsigned char)k;
                k = sm_prev[w * KN + k];
            }
            s_path[t][0] = (unsigned char)k;
        }
        s_we[t] = we;
        meta[b * KN + t] = we;
        meta[(size_t)B * KN + b * KN + t] = e;
    }
    __syncthreads();

    // ---- Phase E: parallel d_j + anchor A/t/f into ws staging (all waves)
    for (int u = t; u < KN * NBND; u += 1024) {
        int r = u / NBND, bp = u - r * NBND;
        int we = s_we[r];
        if (we < 0) continue;
        if (bp <= we) {                          // phase increment d[bp]
            float dv;
            int pj = s_path[r][bp];
            if (bp == 0) {
                const float* Tq = T + pj * CN;
                dv = Tq[8] - Tq[7];              // d_first = pe0 - ps0
            } else {
                int pm = s_path[r][bp - 1];
                float pe_prev = T[((bp - 1) * KN + pm) * CN + 8];
                float psj = T[(bp * KN + pj) * CN + 7];
                float pej = T[(bp * KN + pj) * CN + 8];
                dv = wrapf(psj - pe_prev) + pej - psj;
            }
            s_d[r][bp] = dv;
        }
        int L = we + 1;
        if (bp <= L) {
            float aA, at, af;
            if (bp == 0) {
                const float* Tq = T + (int)s_path[r][0] * CN;
                at = Tq[1]; af = Tq[3]; aA = Tq[5];
            } else if (bp == L) {
                const float* Tq = T + (we * KN + (int)s_path[r][we]) * CN;
                at = Tq[2]; af = Tq[4]; aA = Tq[6];
            } else {
                const float* Ta = T + ((bp - 1) * KN + (int)s_path[r][bp - 1]) * CN;
                const float* Tb = T + (bp * KN + (int)s_path[r][bp]) * CN;
                at = (Ta[2] + Tb[1]) * 0.5f;
                af = (Ta[4] + Tb[3]) * 0.5f;
                aA = (Ta[6] + Tb[5]) * 0.5f;
            }
            float* arow = (float*)(anchors + ((size_t)b * KN + r) * NBND + bp);
            arow[0] = aA; arow[1] = at; arow[3] = af;   // z written in Phase F
        }
    }
    __syncthreads();

    // ---- Phase F: serial phase cumsum per root (32 lanes in parallel;
    // s_d reads have w-independent addresses -> compiler prefetches, chain = adds)
    if (t < KN && s_we[t] >= 0) {
        int we = s_we[t];
        int p0 = s_path[t][0];
        float cum = T[p0 * CN + 7];              // ps0
        float* arow = (float*)(anchors + ((size_t)b * KN + t) * NBND);
        arow[2] = cum;
        for (int j = 0; j <= we; ++j) {
            cum += s_d[t][j];
            arow[(j + 1) * 4 + 2] = cum;
        }
    }
}

// Kernel 3: scatter the <=32 finished anchor rows per batch over the zeros.
__global__ __launch_bounds__(1024) void scatter_kernel(const float4* __restrict__ anchors,
                                                       const int* __restrict__ meta,
                                                       float4* __restrict__ out, int B) {
    const int b = blockIdx.x;
    const int t = threadIdx.x;
    for (int u = t; u < KN * NBND; u += 1024) {
        int r = u / NBND, bp = u - r * NBND;
        int we = meta[b * KN + r];
        if (we < 0 || bp > we + 1) continue;
        int e = meta[(size_t)B * KN + b * KN + r];
        out[((size_t)b * (WN * KN) + e) * NBND + bp] =
            anchors[((size_t)b * KN + r) * NBND + bp];
    }
}

extern "C" void kernel_launch(void* const* d_in, const int* in_sizes, int n_in,
                              void* d_out, int out_size, void* d_ws, size_t ws_size,
                              hipStream_t stream) {
    const float* tok = (const float*)d_in[0];
    int B = in_sizes[0] / (WN * KN * CN);

    size_t off = 0;
    unsigned* Em = (unsigned*)d_ws;
    off += (size_t)B * 127 * KN * sizeof(unsigned);
    off = (off + 255) & ~(size_t)255;
    float* snrP = (float*)((char*)d_ws + off);
    off += (size_t)B * WN * KN * sizeof(float);
    off = (off + 255) & ~(size_t)255;
    unsigned* Un = (unsigned*)((char*)d_ws + off);
    off += (size_t)B * 127 * sizeof(unsigned);
    off = (off + 255) & ~(size_t)255;
    float4* anchors = (float4*)((char*)d_ws + off);
    off += (size_t)B * KN * NBND * sizeof(float4);
    off = (off + 255) & ~(size_t)255;
    int* meta = (int*)((char*)d_ws + off);

    long total4 = (long)out_size / 4;

    hipLaunchKernelGGL(edge_kernel, dim3(B * 127), dim3(1024), 0, stream, tok, Em, snrP, Un);
    hipLaunchKernelGGL(mega_kernel, dim3(B + 2032), dim3(1024), 0, stream,
                       tok, Em, snrP, Un, anchors, meta, (float4*)d_out, total4, B);
    hipLaunchKernelGGL(scatter_kernel, dim3(B), dim3(1024), 0, stream,
                       anchors, meta, (float4*)d_out, B);
}

// Round 5
// 54.668 us; speedup vs baseline: 2.2159x; 2.2159x over previous
//
#include <hip/hip_runtime.h>

#define WN 128
#define KN 32
#define CN 9
#define NBND 129           // W+1 boundary positions
#define NEGF (-1e30f)

// jnp floor-mod based wrap: (x + pi) % (2pi) - pi
__device__ __forceinline__ float wrapf(float x) {
    const float PIf  = 3.14159265358979323846f;
    const float TPIf = 6.28318530717958647692f;
    float a = x + PIf;
    float r = fmodf(a, TPIf);
    if (r < 0.0f) r += TPIf;
    return r - PIf;
}

// Kernel 1: zero-fill the 135MB output (write-bound, dominates) + edge
// feasibility masks (32-bit kp-mask per (b,w,kn)) + packed snr + per-step
// union-of-masks Un[b][w].
__global__ __launch_bounds__(1024) void edge_zero_kernel(const float* __restrict__ tok,
                                                         unsigned* __restrict__ Em,
                                                         float* __restrict__ snrP,
                                                         unsigned* __restrict__ Un,
                                                         float4* __restrict__ outz,
                                                         long total4) {
    __shared__ unsigned s_un;
    const int t = threadIdx.x;
    if (t == 0) s_un = 0u;

    // ---- zero-fill slice (coalesced grid-stride float4)
    long i = (long)blockIdx.x * 1024 + t;
    long stride = (long)gridDim.x * 1024;
    float4 z = make_float4(0.f, 0.f, 0.f, 0.f);
    for (; i < total4; i += stride) outz[i] = z;

    // ---- edge feasibility
    const int b = blockIdx.x / 127;
    const int w = blockIdx.x - b * 127;        // 0..126 (prev window)
    const int kp = t & 31;                     // prev token
    const int kn = t >> 5;                     // cur token (0..31)
    __syncthreads();                           // s_un init visible

    const float* Tp = tok + (((size_t)b * WN + w) * KN + kp) * CN;
    const float* Tc = tok + (((size_t)b * WN + w + 1) * KN + kn) * CN;

    float fe = Tp[4], fs = Tc[3];
    float fm = (fe + fs) * 0.5f;
    bool ok_f = (fm <= 0.0f) || (fabsf(fe - fs) / (fm > 0.0f ? fm : 1.0f) <= 0.05f);
    float dphi = wrapf(Tc[7] - Tp[8]);
    bool ok_p = fabsf(dphi) <= 0.5f;
    float ae = Tp[6], an = Tc[5];
    float am = fmaxf(ae, an);
    bool ok_a = (am <= 0.0f) || (fabsf(ae - an) / (am > 0.0f ? am : 1.0f) <= 0.5f);
    bool ok = (Tp[0] > 0.0f) && (Tc[0] > 0.0f) && ok_f && ok_p && ok_a;

    unsigned long long bal = __ballot(ok);
    int lw = t & 63;
    unsigned lo = (unsigned)(bal & 0xffffffffull);
    unsigned hi = (unsigned)(bal >> 32);
    if (lw == 0) {
        Em[((size_t)b * 127 + w) * KN + kn] = lo;
        if ((lo | hi) != 0u) atomicOr(&s_un, lo | hi);
    } else if (lw == 32) {
        Em[((size_t)b * 127 + w) * KN + kn] = hi;
    }

    if (kp == 0) snrP[((size_t)b * WN + (w + 1)) * KN + kn] = Tc[0];
    if (w == 0 && t < KN) snrP[(size_t)b * WN * KN + t] = tok[(((size_t)b * WN) * KN + t) * CN + 0];
    __syncthreads();
    if (t == 0) Un[b * 127 + w] = s_un;
}

// Kernel 2: one 64-lane wave per batch. Register-resident Viterbi DP with
// readlane broadcasts (best + root piggybacked), early-exit when all chains
// die, in-loop greedy keys, backtrack, and direct anchor writes into the
// already-zeroed output. No __syncthreads (single wave).
__global__ __launch_bounds__(64) void dp_kernel(const float* __restrict__ tok,
                                                const unsigned* __restrict__ Em,
                                                const float* __restrict__ snrP,
                                                const unsigned* __restrict__ Un,
                                                float* __restrict__ out) {
    const int b = blockIdx.x;
    const int t = threadIdx.x;
    const int kn = t & 31;
    const float* T = tok + (size_t)b * WN * KN * CN;

    __shared__ signed char sm_prev[WN * KN];   // 4 KB
    __shared__ unsigned long long s_key[KN];
    __shared__ unsigned char s_path[KN][WN];
    __shared__ float s_d[KN][NBND];
    __shared__ int s_we[KN];
    __shared__ int s_e[KN];

    if (t < KN) { s_key[t] = 0ull; s_we[t] = -1; }

    const unsigned* Ub = Un + (size_t)b * 127;
    int unA = (t < 127) ? (int)Ub[t] : 0;                // Un[0..63]
    int unB = (t + 64 < 127) ? (int)Ub[t + 64] : 0;      // Un[64..126]

    const unsigned* Eb = Em + (size_t)b * 127 * KN;
    const float* Sb = snrP + (size_t)b * WN * KN;

    float s0 = Sb[kn];
    float best = (s0 > 0.0f) ? s0 : NEGF;
    int root = kn;
    unsigned mask_cur = Eb[kn];                // masks for step w=1
    float sn_cur = Sb[KN + kn];

    int w = 1;
    for (; w < WN; ++w) {
        if (__ballot(best > NEGF) == 0ull) break;        // monotone death
        unsigned mask_nxt = 0; float sn_nxt = 0.0f;
        if (w < WN - 1) {                                // prefetch next step
            mask_nxt = Eb[w * KN + kn];
            sn_nxt = Sb[(w + 1) * KN + kn];
        }
        const int wi = w - 1;
        int ua = __builtin_amdgcn_readlane(unA, wi & 63);
        int ubv = __builtin_amdgcn_readlane(unB, wi & 63);
        unsigned un = (unsigned)((wi < 64) ? ua : ubv);  // uniform (SGPR)

        float v = NEGF;
        int idx = 0, nr = 0;
        while (un) {                                     // sparse: ~1-3 bits
            int i = __builtin_ctz(un);
            un &= un - 1u;
            float bv = __int_as_float(
                __builtin_amdgcn_readlane(__float_as_int(best), i));
            int rv = __builtin_amdgcn_readlane(root, i);
            bool c = ((mask_cur >> i) & 1u) && (bv > v); // strict > = first-argmax
            v = c ? bv : v;
            idx = c ? i : idx;
            nr = c ? rv : nr;
        }
        bool reached = v > -5e29f;                       // bf > NEG*0.5
        float te = v + sn_cur;
        if (t < 32) sm_prev[w * KN + kn] = reached ? (signed char)idx : (signed char)-1;
        if (reached) {
            root = nr;
            best = te;
            if (t < 32) {                                // greedy key (per-root max)
                unsigned ubk = __float_as_uint(te);
                ubk ^= (ubk >> 31) ? 0xFFFFFFFFu : 0x80000000u;
                unsigned e = (unsigned)(w * KN + kn);
                unsigned long long key =
                    ((unsigned long long)ubk << 32) | (unsigned long long)(0xFFFFFFFFu - e);
                atomicMax(&s_key[root], key);
            }
        } else {
            best = NEGF;
        }
        mask_cur = mask_nxt;
        sn_cur = sn_nxt;
    }
    // fill untouched prev entries (steps never reached after death)
    for (int i2 = w * KN + t; i2 < WN * KN; i2 += 64) sm_prev[i2] = (signed char)-1;

    // ---- backtrack selected chain per root (32 lanes in parallel)
    if (t < KN) {
        unsigned long long key = s_key[t];
        if (key != 0ull) {
            int e = (int)(0xFFFFFFFFu - (unsigned)(key & 0xFFFFFFFFull));
            int we = e >> 5;
            s_we[t] = we;
            s_e[t] = e;
            int k = e & 31;
            for (int ww = we; ww > 0; --ww) {
                s_path[t][ww] = (unsigned char)k;
                k = sm_prev[ww * KN + k];
            }
            s_path[t][0] = (unsigned char)k;
        }
    }

    // ---- phase increments d_j + anchor A/t/f written DIRECTLY to out
    float* Ob = out + (size_t)b * (WN * KN) * NBND * 4;
    for (int u = t; u < KN * NBND; u += 64) {
        int r = u / NBND, bp = u - r * NBND;
        int we = s_we[r];
        if (we < 0) continue;
        if (bp <= we) {
            float dv;
            int pj = s_path[r][bp];
            if (bp == 0) {
                const float* Tq = T + pj * CN;
                dv = Tq[8] - Tq[7];              // d_first = pe0 - ps0 (ws == 0)
            } else {
                int pm = s_path[r][bp - 1];
                float pe_prev = T[((bp - 1) * KN + pm) * CN + 8];
                float psj = T[(bp * KN + pj) * CN + 7];
                float pej = T[(bp * KN + pj) * CN + 8];
                dv = wrapf(psj - pe_prev) + pej - psj;
            }
            s_d[r][bp] = dv;
        }
        int L = we + 1;
        if (bp <= L) {
            float aA, at, af;
            if (bp == 0) {
                const float* Tq = T + (int)s_path[r][0] * CN;
                at = Tq[1]; af = Tq[3]; aA = Tq[5];
            } else if (bp == L) {
                const float* Tq = T + (we * KN + (int)s_path[r][we]) * CN;
                at = Tq[2]; af = Tq[4]; aA = Tq[6];
            } else {
                const float* Ta = T + ((bp - 1) * KN + (int)s_path[r][bp - 1]) * CN;
                const float* Tb = T + (bp * KN + (int)s_path[r][bp]) * CN;
                at = (Ta[2] + Tb[1]) * 0.5f;
                af = (Ta[4] + Tb[3]) * 0.5f;
                aA = (Ta[6] + Tb[5]) * 0.5f;
            }
            float* arow = Ob + ((size_t)s_e[r] * NBND + bp) * 4;
            arow[0] = aA; arow[1] = at; arow[3] = af;    // [2]=phi below
        }
    }

    // ---- serial phase cumsum per root, direct to out
    if (t < KN && s_we[t] >= 0) {
        int we = s_we[t];
        int p0 = s_path[t][0];
        float cum = T[p0 * CN + 7];              // ps0
        float* arow = Ob + (size_t)s_e[t] * NBND * 4;
        arow[2] = cum;
        for (int j = 0; j <= we; ++j) {
            cum += s_d[t][j];
            arow[(j + 1) * 4 + 2] = cum;
        }
    }
}

extern "C" void kernel_launch(void* const* d_in, const int* in_sizes, int n_in,
                              void* d_out, int out_size, void* d_ws, size_t ws_size,
                              hipStream_t stream) {
    const float* tok = (const float*)d_in[0];
    int B = in_sizes[0] / (WN * KN * CN);

    size_t off = 0;
    unsigned* Em = (unsigned*)d_ws;
    off += (size_t)B * 127 * KN * sizeof(unsigned);
    off = (off + 255) & ~(size_t)255;
    float* snrP = (float*)((char*)d_ws + off);
    off += (size_t)B * WN * KN * sizeof(float);
    off = (off + 255) & ~(size_t)255;
    unsigned* Un = (unsigned*)((char*)d_ws + off);

    long total4 = (long)out_size / 4;

    hipLaunchKernelGGL(edge_zero_kernel, dim3(B * 127), dim3(1024), 0, stream,
                       tok, Em, snrP, Un, (float4*)d_out, total4);
    hipLaunchKernelGGL(dp_kernel, dim3(B), dim3(64), 0, stream,
                       tok, Em, snrP, Un, (float*)d_out);
}